// Round 9
// baseline (404.311 us; speedup 1.0000x reference)
//
#include <hip/hip_runtime.h>
#include <hip/hip_bf16.h>

#define N_NODES 50000
#define N_EDGES 800000
#define N_REL   4
#define D       128
#define NE      (N_REL * N_EDGES)   // 3200000 edges

#define S_SEG   64                  // edge segments; rel = seg>>4
#define SEG_E   (NE / S_SEG)        // 50000 edges per segment
#define G_RANGES 8
#define RPG     (N_NODES / G_RANGES) // 6250 rows per range

#define NCNT    (N_NODES * S_SEG)   // 3200000 (row,seg) cells
#define SCAN_CHUNK 4096
#define NBLK ((NCNT + SCAN_CHUNK - 1) / SCAN_CHUNK)   // 782

// ---------------------------------------------------------------------------
// ws layout (bytes), phase-sequenced aliases; total = 103,200,000 exactly
// (the R1-proven watermark):
//   BST  @ 0         : 3.2M i32 [row][seg] counts->starts    12,800,000
//     (alias after k_gax: WT2 bf16 128x640 [n][k] = 163,840)
//   INV2 @ 12800000  : 200000 f32 inv_sqrt [node*4+rel]         800,000
//   EREC @ 13600000  : 3.2M int2 (col, raw val)             25,600,000
//     (alias during count..tr: CNTT 64x50000 i32)
//   AXC  @ 39200000  : 50000 x 640 bf16 rows:               64,000,000
//       cols 0:128   = Xb (bf16 X), cols 128+r*128.. = AX_r
//     (aliases during sort phase, all dead before k_prep_x:
//       RANK u16 3.2M @ +0 = 6,400,000
//       BSUM  782 i32 @ +6,400,000 ; BOFF @ +6,403,200)
// ---------------------------------------------------------------------------
#define OFF_BST   0
#define OFF_INV2  12800000
#define OFF_EREC  13600000
#define OFF_AXC   39200000

typedef __attribute__((ext_vector_type(8))) short bf16x8;
typedef __attribute__((ext_vector_type(4))) float f32x4;

__device__ inline unsigned short f2bf(float f) {
    unsigned u = __float_as_uint(f);
    u += 0x7fffu + ((u >> 16) & 1u);
    return (unsigned short)(u >> 16);
}

// --- LDS counting: block (seg, row-range). Zero global atomics. ------------
__global__ __launch_bounds__(256) void k_count(const int* __restrict__ rows,
                                               int* __restrict__ cntt,
                                               unsigned short* __restrict__ rank) {
    __shared__ int lc[RPG];                      // 25 KB
    const int seg = blockIdx.x >> 3;
    const int g = blockIdx.x & 7;
    const int rbase = g * RPG;
    for (int i = threadIdx.x; i < RPG; i += 256) lc[i] = 0;
    __syncthreads();
    const int4* r4 = (const int4*)(rows + (size_t)seg * SEG_E);
    const int n4 = SEG_E / 4;                    // 12500
    for (int i = threadIdx.x; i < n4; i += 256) {
        int4 v = r4[i];
        int t = seg * SEG_E + i * 4;
        unsigned int l0 = (unsigned int)(v.x - rbase);
        unsigned int l1 = (unsigned int)(v.y - rbase);
        unsigned int l2 = (unsigned int)(v.z - rbase);
        unsigned int l3 = (unsigned int)(v.w - rbase);
        if (l0 < (unsigned int)RPG) rank[t]     = (unsigned short)atomicAdd(&lc[l0], 1);
        if (l1 < (unsigned int)RPG) rank[t + 1] = (unsigned short)atomicAdd(&lc[l1], 1);
        if (l2 < (unsigned int)RPG) rank[t + 2] = (unsigned short)atomicAdd(&lc[l2], 1);
        if (l3 < (unsigned int)RPG) rank[t + 3] = (unsigned short)atomicAdd(&lc[l3], 1);
    }
    __syncthreads();
    for (int i = threadIdx.x; i < RPG; i += 256)
        cntt[(size_t)seg * N_NODES + rbase + i] = lc[i];
}

// --- transpose cntt[seg][row] -> bst[row][seg], 64x64 tiles ----------------
__global__ __launch_bounds__(256) void k_tr(const int* __restrict__ cntt,
                                            int* __restrict__ bst) {
    __shared__ int tile[64][65];
    const int r0 = blockIdx.x * 64;
    const int l = threadIdx.x & 63;
    const int q = threadIdx.x >> 6;
#pragma unroll
    for (int p = 0; p < 16; ++p) {
        int seg = q * 16 + p;
        int row = r0 + l;
        tile[seg][l] = (row < N_NODES) ? cntt[(size_t)seg * N_NODES + row] : 0;
    }
    __syncthreads();
#pragma unroll
    for (int p = 0; p < 16; ++p) {
        int rr = q * 16 + p;
        int row = r0 + rr;
        if (row < N_NODES) bst[(size_t)row * S_SEG + l] = tile[l][rr];
    }
}

// --- scan over 3.2M (row,seg) counts, in place (16 cells/thread) -----------
__global__ __launch_bounds__(256) void k_scanA(int* __restrict__ bst,
                                               int* __restrict__ bsum) {
    __shared__ int s[256];
    int t = threadIdx.x;
    int base = blockIdx.x * SCAN_CHUNK + t * 16;
    int4 v[4];
    int tsum = 0;
#pragma unroll
    for (int q = 0; q < 4; ++q) {
        int idx = base + q * 4;
        if (idx < NCNT) v[q] = *(const int4*)(bst + idx);
        else v[q] = make_int4(0, 0, 0, 0);
        tsum += v[q].x + v[q].y + v[q].z + v[q].w;
    }
    s[t] = tsum;
    __syncthreads();
    for (int off = 1; off < 256; off <<= 1) {
        int x = (t >= off) ? s[t - off] : 0;
        __syncthreads();
        s[t] += x;
        __syncthreads();
    }
    int run = s[t] - tsum;
#pragma unroll
    for (int q = 0; q < 4; ++q) {
        int idx = base + q * 4;
        if (idx < NCNT) {
            int4 o;
            o.x = run; run += v[q].x;
            o.y = run; run += v[q].y;
            o.z = run; run += v[q].z;
            o.w = run; run += v[q].w;
            *(int4*)(bst + idx) = o;
        }
    }
    if (t == 255) bsum[blockIdx.x] = s[255];
}

__global__ __launch_bounds__(256) void k_scanB(const int* __restrict__ bsum,
                                               int* __restrict__ boff) {
    __shared__ int s[256];
    int t = threadIdx.x;
    int b = t * 4;
    int v0 = (b     < NBLK) ? bsum[b]     : 0;
    int v1 = (b + 1 < NBLK) ? bsum[b + 1] : 0;
    int v2 = (b + 2 < NBLK) ? bsum[b + 2] : 0;
    int v3 = (b + 3 < NBLK) ? bsum[b + 3] : 0;
    int tsum = v0 + v1 + v2 + v3;
    s[t] = tsum;
    __syncthreads();
    for (int off = 1; off < 256; off <<= 1) {
        int x = (t >= off) ? s[t - off] : 0;
        __syncthreads();
        s[t] += x;
        __syncthreads();
    }
    int excl = s[t] - tsum;
    if (b     < NBLK) boff[b]     = excl;
    if (b + 1 < NBLK) boff[b + 1] = excl + v0;
    if (b + 2 < NBLK) boff[b + 2] = excl + v0 + v1;
    if (b + 3 < NBLK) boff[b + 3] = excl + v0 + v1 + v2;
}

__global__ __launch_bounds__(256) void k_scanC(int* __restrict__ bst,
                                               const int* __restrict__ boff) {
    int t = threadIdx.x;
    int base = blockIdx.x * SCAN_CHUNK + t * 16;
    int add = boff[blockIdx.x];
#pragma unroll
    for (int q = 0; q < 4; ++q) {
        int idx = base + q * 4;
        if (idx < NCNT) {
            int4 v = *(const int4*)(bst + idx);
            v.x += add; v.y += add; v.z += add; v.w += add;
            *(int4*)(bst + idx) = v;
        }
    }
}

// --- fill CSR records (col, raw val), fully atomic-free --------------------
__global__ __launch_bounds__(256) void k_fill(const int* __restrict__ rows,
                                              const int* __restrict__ cols,
                                              const float* __restrict__ vals,
                                              const int* __restrict__ bst,
                                              const unsigned short* __restrict__ rank,
                                              int2* __restrict__ erec) {
    int t = blockIdx.x * 256 + threadIdx.x;
    if (t >= NE) return;
    int seg = t / SEG_E;                 // const-div
    int row = rows[t], col = cols[t];
    int pos = bst[(size_t)row * S_SEG + seg] + (int)rank[t];
    erec[pos] = make_int2(col, __float_as_int(vals[t]));
}

// --- degree: thread per (row,rel), contiguous record-run sum ---------------
__global__ __launch_bounds__(256) void k_deg(const int* __restrict__ bst,
                                             const int2* __restrict__ erec,
                                             float* __restrict__ inv2) {
    int t = blockIdx.x * 256 + threadIdx.x;
    if (t >= N_NODES * 4) return;
    int row = t >> 2, rel = t & 3;
    int s = bst[(size_t)row * S_SEG + rel * 16];
    int e = (rel < 3) ? bst[(size_t)row * S_SEG + rel * 16 + 16]
                      : ((row + 1 < N_NODES) ? bst[(size_t)(row + 1) * S_SEG] : NE);
    float acc = 0.f;
    for (int i = s; i < e; ++i) acc += __int_as_float(erec[i].y);
    inv2[t] = rsqrtf(fmaxf(acc, 1e-12f));
}

// --- prep: X f32 -> bf16 into AXc cols 0:128 -------------------------------
__global__ __launch_bounds__(256) void k_prep_x(const float* __restrict__ X,
                                                unsigned short* __restrict__ AXc) {
    int id = blockIdx.x * 256 + threadIdx.x;     // 1.6M ushort4 chunks
    int row = id >> 5, c4 = id & 31;
    float4 v = *(const float4*)(X + (size_t)row * 128 + c4 * 4);
    ushort4 h;
    h.x = f2bf(v.x); h.y = f2bf(v.y); h.z = f2bf(v.z); h.w = f2bf(v.w);
    *(ushort4*)(AXc + (size_t)row * 640 + c4 * 4) = h;
}

// --- prep: W stack -> Wt2 bf16 [n][k], k 0:128=Wself, 128+r*128+kk=Wrel[r] -
__global__ __launch_bounds__(256) void k_prep_w(const float* __restrict__ Wself,
                                                const float* __restrict__ Wrel,
                                                unsigned short* __restrict__ Wt2) {
    int id = blockIdx.x * 256 + threadIdx.x;     // 128*640 = 81920
    int n = id / 640;
    int k = id - n * 640;
    float v;
    if (k < 128) v = Wself[k * 128 + n];
    else {
        int r = (k - 128) >> 7, kk = (k - 128) & 127;
        v = Wrel[((size_t)r * 128 + kk) * 128 + n];
    }
    Wt2[(size_t)n * 640 + k] = f2bf(v);
}

// --- gather on X: AX_r[row] = sum coef * Xb[col]; working set 12.8 MB ------
__global__ __launch_bounds__(256, 8) void k_gax(const int* __restrict__ bst,
                                                const int2* __restrict__ erec,
                                                const float* __restrict__ inv2,
                                                unsigned int* __restrict__ AXu) {
    const int wid = threadIdx.x >> 6;
    const int lane = threadIdx.x & 63;
    const int row = blockIdx.x * 4 + wid;
    if (row >= N_NODES) return;

    const int bend = (row + 1 < N_NODES) ? bst[(size_t)(row + 1) * S_SEG] : NE;

    for (int rel = 0; rel < 4; rel++) {
        const float selfinv = inv2[(size_t)row * 4 + rel];
        const int s = bst[(size_t)row * S_SEG + rel * 16];
        const int e = (rel < 3) ? bst[(size_t)row * S_SEG + rel * 16 + 16] : bend;
        float ax0 = 0.f, ay0 = 0.f;
        for (int base = s; base < e; base += 64) {
            const int rem = e - base;
            int pcL = 0;
            float cfL = 0.f;
            if (lane < rem) {
                int2 rec = erec[base + lane];
                pcL = rec.x;
                cfL = __int_as_float(rec.y) * selfinv * inv2[(size_t)rec.x * 4 + rel];
            }
            if (rem >= 64) {
#pragma unroll
                for (int i = 0; i < 64; ++i) {
                    int pc = __builtin_amdgcn_readlane(pcL, i);
                    float cf = __int_as_float(__builtin_amdgcn_readlane(__float_as_int(cfL), i));
                    unsigned int y = AXu[(size_t)pc * 320 + lane];
                    ax0 = fmaf(cf, __uint_as_float(y << 16), ax0);
                    ay0 = fmaf(cf, __uint_as_float(y & 0xffff0000u), ay0);
                }
            } else {
                for (int i = 0; i < rem; ++i) {
                    int pc = __builtin_amdgcn_readlane(pcL, i);
                    float cf = __int_as_float(__builtin_amdgcn_readlane(__float_as_int(cfL), i));
                    unsigned int y = AXu[(size_t)pc * 320 + lane];
                    ax0 = fmaf(cf, __uint_as_float(y << 16), ax0);
                    ay0 = fmaf(cf, __uint_as_float(y & 0xffff0000u), ay0);
                }
            }
        }
        unsigned int lo = f2bf(ax0);
        unsigned int hi = f2bf(ay0);
        AXu[(size_t)row * 320 + 64 + rel * 64 + lane] = (hi << 16) | lo;
    }
}

// --- final GEMM: out = AXc(50000x640) @ Wt2^T(640x128) + bias --------------
// 128-row tile, 4 waves 2x2, each 64x64; K-loop 20 steps of 32.
__global__ __launch_bounds__(256) void k_mm2(const unsigned short* __restrict__ AXc,
                                             const unsigned short* __restrict__ Wt2,
                                             const float* __restrict__ bias,
                                             float* __restrict__ out) {
    const int m0 = blockIdx.x * 128;
    const int tid = threadIdx.x;
    const int wave = tid >> 6, lane = tid & 63;
    const int wm = wave >> 1, wn = wave & 1;

    __shared__ unsigned short As[128][40];

    const f32x4 zero = {0.f, 0.f, 0.f, 0.f};
    f32x4 acc[4][4];
#pragma unroll
    for (int i = 0; i < 4; i++)
#pragma unroll
        for (int j = 0; j < 4; j++) acc[i][j] = zero;

    const int lr = lane & 15;
    const int kb = (lane >> 4) * 8;

    for (int k0 = 0; k0 < 640; k0 += 32) {
#pragma unroll
        for (int l = 0; l < 2; l++) {
            int id = tid + l * 256;
            int row = id >> 2, c4 = id & 3;
            int gr = m0 + row;
            int4 v = make_int4(0, 0, 0, 0);
            if (gr < N_NODES)
                v = *(const int4*)(AXc + (size_t)gr * 640 + k0 + c4 * 8);
            *(int4*)&As[row][c4 * 8] = v;
        }
        __syncthreads();

        bf16x8 a[4], b[4];
#pragma unroll
        for (int i = 0; i < 4; i++)
            a[i] = *(const bf16x8*)&As[wm * 64 + i * 16 + lr][kb];
#pragma unroll
        for (int j = 0; j < 4; j++)
            b[j] = *(const bf16x8*)(Wt2 + (size_t)(wn * 64 + j * 16 + lr) * 640 + k0 + kb);
#pragma unroll
        for (int i = 0; i < 4; i++)
#pragma unroll
            for (int j = 0; j < 4; j++)
                acc[i][j] = __builtin_amdgcn_mfma_f32_16x16x32_bf16(a[i], b[j], acc[i][j], 0, 0, 0);
        __syncthreads();
    }

    const int lrow = (lane >> 4) * 4;
    const int lcol = lane & 15;
#pragma unroll
    for (int i = 0; i < 4; i++) {
#pragma unroll
        for (int j = 0; j < 4; j++) {
            int gc = wn * 64 + j * 16 + lcol;
            float bv = bias[gc];
#pragma unroll
            for (int v = 0; v < 4; v++) {
                int gr = m0 + wm * 64 + i * 16 + lrow + v;
                if (gr < N_NODES)
                    out[(size_t)gr * 128 + gc] = acc[i][j][v] + bv;
            }
        }
    }
}

extern "C" void kernel_launch(void* const* d_in, const int* in_sizes, int n_in,
                              void* d_out, int out_size, void* d_ws, size_t ws_size,
                              hipStream_t stream) {
    const float* X     = (const float*)d_in[0];
    const int*   rows  = (const int*)d_in[1];
    const int*   cols  = (const int*)d_in[2];
    const float* vals  = (const float*)d_in[3];
    const float* Wrel  = (const float*)d_in[4];
    const float* Wself = (const float*)d_in[5];
    const float* bias  = (const float*)d_in[6];
    float* out = (float*)d_out;

    char* ws = (char*)d_ws;
    int*   bst  = (int*)(ws + OFF_BST);
    float* inv2 = (float*)(ws + OFF_INV2);
    int2*  erec = (int2*)(ws + OFF_EREC);
    int*   cntt = (int*)(ws + OFF_EREC);                    // alias (count..tr)
    unsigned short* AXc = (unsigned short*)(ws + OFF_AXC);
    unsigned short* rank = (unsigned short*)(ws + OFF_AXC); // alias (count..fill)
    int*   bsum = (int*)(ws + OFF_AXC + 6400000);           // alias (scan phase)
    int*   boff = (int*)(ws + OFF_AXC + 6403200);           // alias (scan phase)
    unsigned short* Wt2 = (unsigned short*)(ws + OFF_BST);  // alias (after gax)

    // --- phase 1: counting sort of edges by (row, seg) ---
    k_count<<<S_SEG * G_RANGES, 256, 0, stream>>>(rows, cntt, rank);
    k_tr<<<(N_NODES + 63) / 64, 256, 0, stream>>>(cntt, bst);
    k_scanA<<<NBLK, 256, 0, stream>>>(bst, bsum);
    k_scanB<<<1, 256, 0, stream>>>(bsum, boff);
    k_scanC<<<NBLK, 256, 0, stream>>>(bst, boff);
    k_fill<<<(NE + 255) / 256, 256, 0, stream>>>(rows, cols, vals, bst, rank, erec);
    k_deg<<<(N_NODES * 4 + 255) / 256, 256, 0, stream>>>(bst, erec, inv2);

    // --- phase 2: gather on X (rank/bsum/boff dead; AXC region now live) ---
    k_prep_x<<<6250, 256, 0, stream>>>(X, AXc);
    k_gax<<<(N_NODES + 3) / 4, 256, 0, stream>>>(bst, erec, inv2,
                                                 (unsigned int*)AXc);

    // --- phase 3: single stacked-K GEMM (bst dead -> Wt2 aliases it) ---
    k_prep_w<<<320, 256, 0, stream>>>(Wself, Wrel, Wt2);
    k_mm2<<<(N_NODES + 127) / 128, 256, 0, stream>>>(AXc, Wt2, bias, out);
}

// Round 10
// 347.781 us; speedup vs baseline: 1.1625x; 1.1625x over previous
//
#include <hip/hip_runtime.h>
#include <hip/hip_bf16.h>

#define N_NODES 50000
#define N_EDGES 800000
#define N_REL   4
#define D       128
#define NE      (N_REL * N_EDGES)   // 3200000 edges

#define S_SEG   64                  // edge segments; rel = seg>>4
#define SEG_E   (NE / S_SEG)        // 50000 edges per segment
#define G_RANGES 8
#define RPG     (N_NODES / G_RANGES) // 6250 rows per range

#define NCNT    (N_NODES * S_SEG)   // 3200000 (row,seg) cells
#define SCAN_CHUNK 4096
#define NBLK ((NCNT + SCAN_CHUNK - 1) / SCAN_CHUNK)   // 782

// ---------------------------------------------------------------------------
// ws layout (bytes) — zero global atomics, no memset (identical to R8):
//   BST   @ 0        : 3.2M i32 [row][seg] counts->starts     12,800,000
//   BSUM  @ 12800000 : 782 i32 (pad 3200)
//   BOFF  @ 12803200 : 782 i32 (pad 3200)
//   EREC  @ 12806400 : 3.2M int2 (pc=r*N+col, raw val)        25,600,000
//     (aliases, sequentially dead: WT bf16 5*128*128 [prep_w..mm];
//      CNTT 64x50000 i32 [count..tr])
//   Y     @ 38406400 : 4*50000*128 bf16                       51,200,000
//   RANK  @ 89606400 : 3.2M u16                                6,400,000
//   INV2  @ 96006400 : 200000 f32                                800,000
// total 96.8 MB < 103.2 MB proven watermark (R1)
// ---------------------------------------------------------------------------
#define OFF_BST   0
#define OFF_BSUM  12800000
#define OFF_BOFF  12803200
#define OFF_EREC  12806400
#define OFF_Y     38406400
#define OFF_RANK  89606400
#define OFF_INV2  96006400

typedef __attribute__((ext_vector_type(8))) short bf16x8;
typedef __attribute__((ext_vector_type(4))) float f32x4;

__device__ inline unsigned short f2bf(float f) {
    unsigned u = __float_as_uint(f);
    u += 0x7fffu + ((u >> 16) & 1u);
    return (unsigned short)(u >> 16);
}

// --- prep: W (f32 [k][n]) -> Wt bf16 [seg][n][k] ---------------------------
__global__ __launch_bounds__(256) void k_prep_w(const float* __restrict__ Wself,
                                                const float* __restrict__ Wrel,
                                                unsigned short* __restrict__ Wt) {
    int id = blockIdx.x * 256 + threadIdx.x;
    int seg = id >> 14;
    int rem = id & 16383;
    int n = rem >> 7, k = rem & 127;
    float v = (seg == 0) ? Wself[k * 128 + n] : Wrel[(size_t)(seg - 1) * 16384 + k * 128 + n];
    Wt[id] = f2bf(v);
}

// --- fused 5-panel MFMA GEMM: 64-row tile, X staged once, W from global ----
__global__ __launch_bounds__(256) void k_mm(const float* __restrict__ X,
                                            const unsigned short* __restrict__ Wt,
                                            const float* __restrict__ bias,
                                            float* __restrict__ out,
                                            unsigned short* __restrict__ Yb) {
    const int m0 = blockIdx.x * 64;
    const int tid = threadIdx.x;
    const int wave = tid >> 6, lane = tid & 63;
    const int wm = wave >> 1, wn = wave & 1;

    __shared__ unsigned short Xs[64][136];

#pragma unroll
    for (int l = 0; l < 8; l++) {
        int c = tid + l * 256;
        int row = c >> 5, c4 = c & 31;
        int gr = m0 + row;
        float4 v = make_float4(0.f, 0.f, 0.f, 0.f);
        if (gr < N_NODES) v = *(const float4*)(X + (size_t)gr * 128 + c4 * 4);
        ushort4 h;
        h.x = f2bf(v.x); h.y = f2bf(v.y); h.z = f2bf(v.z); h.w = f2bf(v.w);
        *(ushort4*)&Xs[row][c4 * 4] = h;
    }
    __syncthreads();

    const int lr = lane & 15;
    const int kb = (lane >> 4) * 8;
    const int lrow = (lane >> 4) * 4;
    const int lcol = lane & 15;
    const f32x4 zero = {0.f, 0.f, 0.f, 0.f};

    for (int seg = 0; seg < 5; seg++) {
        const unsigned short* Wseg = Wt + (size_t)seg * 16384;
        f32x4 acc[2][4];
#pragma unroll
        for (int i = 0; i < 2; i++)
#pragma unroll
            for (int j = 0; j < 4; j++) acc[i][j] = zero;

#pragma unroll
        for (int k0 = 0; k0 < 128; k0 += 32) {
            bf16x8 a[2], b[4];
#pragma unroll
            for (int i = 0; i < 2; i++)
                a[i] = *(const bf16x8*)&Xs[wm * 32 + i * 16 + lr][k0 + kb];
#pragma unroll
            for (int j = 0; j < 4; j++)
                b[j] = *(const bf16x8*)(Wseg + (size_t)(wn * 64 + j * 16 + lr) * 128 + k0 + kb);
#pragma unroll
            for (int i = 0; i < 2; i++)
#pragma unroll
                for (int j = 0; j < 4; j++)
                    acc[i][j] = __builtin_amdgcn_mfma_f32_16x16x32_bf16(a[i], b[j], acc[i][j], 0, 0, 0);
        }

        if (seg == 0) {
#pragma unroll
            for (int i = 0; i < 2; i++) {
#pragma unroll
                for (int j = 0; j < 4; j++) {
                    int gc = wn * 64 + j * 16 + lcol;
                    float bv = bias[gc];
#pragma unroll
                    for (int v = 0; v < 4; v++) {
                        int gr = m0 + wm * 32 + i * 16 + lrow + v;
                        if (gr < N_NODES)
                            out[(size_t)gr * 128 + gc] = acc[i][j][v] + bv;
                    }
                }
            }
        } else {
            unsigned short* Yseg = Yb + (size_t)(seg - 1) * N_NODES * 128;
#pragma unroll
            for (int i = 0; i < 2; i++) {
#pragma unroll
                for (int j = 0; j < 4; j++) {
                    int gc = wn * 64 + j * 16 + lcol;
#pragma unroll
                    for (int v = 0; v < 4; v++) {
                        int gr = m0 + wm * 32 + i * 16 + lrow + v;
                        if (gr < N_NODES)
                            Yseg[(size_t)gr * 128 + gc] = f2bf(acc[i][j][v]);
                    }
                }
            }
        }
    }
}

// --- LDS counting: block (seg, row-range). G=8, int4 loads -----------------
__global__ __launch_bounds__(256) void k_count(const int* __restrict__ rows,
                                               int* __restrict__ cntt,
                                               unsigned short* __restrict__ rank) {
    __shared__ int lc[RPG];                      // 25 KB
    const int seg = blockIdx.x >> 3;
    const int g = blockIdx.x & 7;
    const int rbase = g * RPG;
    for (int i = threadIdx.x; i < RPG; i += 256) lc[i] = 0;
    __syncthreads();
    const int4* r4 = (const int4*)(rows + (size_t)seg * SEG_E);
    const int n4 = SEG_E / 4;                    // 12500
    for (int i = threadIdx.x; i < n4; i += 256) {
        int4 v = r4[i];
        int t = seg * SEG_E + i * 4;
        unsigned int l0 = (unsigned int)(v.x - rbase);
        unsigned int l1 = (unsigned int)(v.y - rbase);
        unsigned int l2 = (unsigned int)(v.z - rbase);
        unsigned int l3 = (unsigned int)(v.w - rbase);
        if (l0 < (unsigned int)RPG) rank[t]     = (unsigned short)atomicAdd(&lc[l0], 1);
        if (l1 < (unsigned int)RPG) rank[t + 1] = (unsigned short)atomicAdd(&lc[l1], 1);
        if (l2 < (unsigned int)RPG) rank[t + 2] = (unsigned short)atomicAdd(&lc[l2], 1);
        if (l3 < (unsigned int)RPG) rank[t + 3] = (unsigned short)atomicAdd(&lc[l3], 1);
    }
    __syncthreads();
    for (int i = threadIdx.x; i < RPG; i += 256)
        cntt[(size_t)seg * N_NODES + rbase + i] = lc[i];
}

// --- transpose cntt[seg][row] -> bst[row][seg], 64x64 tiles ----------------
__global__ __launch_bounds__(256) void k_tr(const int* __restrict__ cntt,
                                            int* __restrict__ bst) {
    __shared__ int tile[64][65];
    const int r0 = blockIdx.x * 64;
    const int l = threadIdx.x & 63;
    const int q = threadIdx.x >> 6;
#pragma unroll
    for (int p = 0; p < 16; ++p) {
        int seg = q * 16 + p;
        int row = r0 + l;
        tile[seg][l] = (row < N_NODES) ? cntt[(size_t)seg * N_NODES + row] : 0;
    }
    __syncthreads();
#pragma unroll
    for (int p = 0; p < 16; ++p) {
        int rr = q * 16 + p;
        int row = r0 + rr;
        if (row < N_NODES) bst[(size_t)row * S_SEG + l] = tile[l][rr];
    }
}

// --- scan over 3.2M (row,seg) counts, in place (16 cells/thread) -----------
__global__ __launch_bounds__(256) void k_scanA(int* __restrict__ bst,
                                               int* __restrict__ bsum) {
    __shared__ int s[256];
    int t = threadIdx.x;
    int base = blockIdx.x * SCAN_CHUNK + t * 16;
    int4 v[4];
    int tsum = 0;
#pragma unroll
    for (int q = 0; q < 4; ++q) {
        int idx = base + q * 4;
        if (idx < NCNT) v[q] = *(const int4*)(bst + idx);
        else v[q] = make_int4(0, 0, 0, 0);
        tsum += v[q].x + v[q].y + v[q].z + v[q].w;
    }
    s[t] = tsum;
    __syncthreads();
    for (int off = 1; off < 256; off <<= 1) {
        int x = (t >= off) ? s[t - off] : 0;
        __syncthreads();
        s[t] += x;
        __syncthreads();
    }
    int run = s[t] - tsum;
#pragma unroll
    for (int q = 0; q < 4; ++q) {
        int idx = base + q * 4;
        if (idx < NCNT) {
            int4 o;
            o.x = run; run += v[q].x;
            o.y = run; run += v[q].y;
            o.z = run; run += v[q].z;
            o.w = run; run += v[q].w;
            *(int4*)(bst + idx) = o;
        }
    }
    if (t == 255) bsum[blockIdx.x] = s[255];
}

__global__ __launch_bounds__(256) void k_scanB(const int* __restrict__ bsum,
                                               int* __restrict__ boff) {
    __shared__ int s[256];
    int t = threadIdx.x;
    int b = t * 4;
    int v0 = (b     < NBLK) ? bsum[b]     : 0;
    int v1 = (b + 1 < NBLK) ? bsum[b + 1] : 0;
    int v2 = (b + 2 < NBLK) ? bsum[b + 2] : 0;
    int v3 = (b + 3 < NBLK) ? bsum[b + 3] : 0;
    int tsum = v0 + v1 + v2 + v3;
    s[t] = tsum;
    __syncthreads();
    for (int off = 1; off < 256; off <<= 1) {
        int x = (t >= off) ? s[t - off] : 0;
        __syncthreads();
        s[t] += x;
        __syncthreads();
    }
    int excl = s[t] - tsum;
    if (b     < NBLK) boff[b]     = excl;
    if (b + 1 < NBLK) boff[b + 1] = excl + v0;
    if (b + 2 < NBLK) boff[b + 2] = excl + v0 + v1;
    if (b + 3 < NBLK) boff[b + 3] = excl + v0 + v1 + v2;
}

__global__ __launch_bounds__(256) void k_scanC(int* __restrict__ bst,
                                               const int* __restrict__ boff) {
    int t = threadIdx.x;
    int base = blockIdx.x * SCAN_CHUNK + t * 16;
    int add = boff[blockIdx.x];
#pragma unroll
    for (int q = 0; q < 4; ++q) {
        int idx = base + q * 4;
        if (idx < NCNT) {
            int4 v = *(const int4*)(bst + idx);
            v.x += add; v.y += add; v.z += add; v.w += add;
            *(int4*)(bst + idx) = v;
        }
    }
}

// --- fill CSR records, fully atomic-free -----------------------------------
__global__ __launch_bounds__(256) void k_fill(const int* __restrict__ rows,
                                              const int* __restrict__ cols,
                                              const float* __restrict__ vals,
                                              const int* __restrict__ bst,
                                              const unsigned short* __restrict__ rank,
                                              int2* __restrict__ erec) {
    int t = blockIdx.x * 256 + threadIdx.x;
    if (t >= NE) return;
    int seg = t / SEG_E;                 // const-div
    int r = seg >> 4;                    // relation
    int row = rows[t], col = cols[t];
    int pos = bst[(size_t)row * S_SEG + seg] + (int)rank[t];
    erec[pos] = make_int2(r * N_NODES + col, __float_as_int(vals[t]));
}

// --- degree: thread per (row,rel), contiguous record-run sum ---------------
__global__ __launch_bounds__(256) void k_deg(const int* __restrict__ bst,
                                             const int2* __restrict__ erec,
                                             float* __restrict__ inv2) {
    int t = blockIdx.x * 256 + threadIdx.x;
    if (t >= N_NODES * 4) return;
    int row = t >> 2, rel = t & 3;
    int s = bst[(size_t)row * S_SEG + rel * 16];
    int e = (rel < 3) ? bst[(size_t)row * S_SEG + rel * 16 + 16]
                      : ((row + 1 < N_NODES) ? bst[(size_t)(row + 1) * S_SEG] : NE);
    float acc = 0.f;
    for (int i = s; i < e; ++i) acc += __int_as_float(erec[i].y);
    inv2[t] = rsqrtf(fmaxf(acc, 1e-12f));
}

// --- gather: wave per row; 16-wide explicit load batches for MLP -----------
__global__ __launch_bounds__(256) void k_gather(const int* __restrict__ bst,
                                                const int2* __restrict__ erec,
                                                const float* __restrict__ inv2,
                                                const unsigned int* __restrict__ Y2,
                                                float* __restrict__ out) {
    const int wid = threadIdx.x >> 6;
    const int lane = threadIdx.x & 63;
    const int row = blockIdx.x * 4 + wid;
    if (row >= N_NODES) return;

    const int start = bst[(size_t)row * S_SEG];
    const int end = (row + 1 < N_NODES) ? bst[(size_t)(row + 1) * S_SEG] : NE;
    const float4 sv = *(const float4*)(inv2 + (size_t)row * 4);

    float ax = 0.f, ay = 0.f;
    for (int base = start; base < end; base += 64) {
        int rem = end - base;
        if (rem > 64) rem = 64;
        int pcL = 0;
        float cfL = 0.f;
        if (lane < rem) {
            int2 rec = erec[base + lane];
            int pc = rec.x;
            int r = (int)((unsigned int)pc / (unsigned int)N_NODES);
            int col = pc - r * N_NODES;
            float selfinv = (r == 0) ? sv.x : (r == 1) ? sv.y : (r == 2) ? sv.z : sv.w;
            cfL = __int_as_float(rec.y) * selfinv * inv2[(size_t)col * 4 + r];
            pcL = pc;
        }
        int c = 0;
        // 16-wide chunks: force 16 independent Y loads in flight
        for (; c + 16 <= rem; c += 16) {
            unsigned int y[16];
            float cf[16];
#pragma unroll
            for (int j = 0; j < 16; ++j) {
                int pc = __builtin_amdgcn_readlane(pcL, c + j);
                cf[j] = __int_as_float(__builtin_amdgcn_readlane(__float_as_int(cfL), c + j));
                y[j] = Y2[(size_t)pc * 64 + lane];
            }
#pragma unroll
            for (int j = 0; j < 16; ++j) {
                ax = fmaf(cf[j], __uint_as_float(y[j] << 16), ax);
                ay = fmaf(cf[j], __uint_as_float(y[j] & 0xffff0000u), ay);
            }
        }
        for (; c < rem; ++c) {
            int pc = __builtin_amdgcn_readlane(pcL, c);
            float cf = __int_as_float(__builtin_amdgcn_readlane(__float_as_int(cfL), c));
            unsigned int y = Y2[(size_t)pc * 64 + lane];
            ax = fmaf(cf, __uint_as_float(y << 16), ax);
            ay = fmaf(cf, __uint_as_float(y & 0xffff0000u), ay);
        }
    }
    float2* op = (float2*)(out + (size_t)row * D) + lane;
    float2 o = *op;
    o.x += ax;
    o.y += ay;
    *op = o;
}

extern "C" void kernel_launch(void* const* d_in, const int* in_sizes, int n_in,
                              void* d_out, int out_size, void* d_ws, size_t ws_size,
                              hipStream_t stream) {
    const float* X     = (const float*)d_in[0];
    const int*   rows  = (const int*)d_in[1];
    const int*   cols  = (const int*)d_in[2];
    const float* vals  = (const float*)d_in[3];
    const float* Wrel  = (const float*)d_in[4];
    const float* Wself = (const float*)d_in[5];
    const float* bias  = (const float*)d_in[6];
    float* out = (float*)d_out;

    char* ws = (char*)d_ws;
    int*   bst  = (int*)(ws + OFF_BST);
    int*   bsum = (int*)(ws + OFF_BSUM);
    int*   boff = (int*)(ws + OFF_BOFF);
    int2*  erec = (int2*)(ws + OFF_EREC);
    int*   cntt = (int*)(ws + OFF_EREC);                   // alias (count..tr)
    unsigned short* Wt = (unsigned short*)(ws + OFF_EREC); // alias (prep_w..mm)
    unsigned short* Yb = (unsigned short*)(ws + OFF_Y);
    unsigned short* rank = (unsigned short*)(ws + OFF_RANK);
    float* inv2 = (float*)(ws + OFF_INV2);

    k_prep_w<<<320, 256, 0, stream>>>(Wself, Wrel, Wt);

    // GEMM consumes Wt; afterwards the EREC region is reused by cntt/erec
    k_mm<<<(N_NODES + 63) / 64, 256, 0, stream>>>(X, Wt, bias, out, Yb);

    k_count<<<S_SEG * G_RANGES, 256, 0, stream>>>(rows, cntt, rank);
    k_tr<<<(N_NODES + 63) / 64, 256, 0, stream>>>(cntt, bst);
    k_scanA<<<NBLK, 256, 0, stream>>>(bst, bsum);
    k_scanB<<<1, 256, 0, stream>>>(bsum, boff);
    k_scanC<<<NBLK, 256, 0, stream>>>(bst, boff);

    k_fill<<<(NE + 255) / 256, 256, 0, stream>>>(rows, cols, vals, bst, rank, erec);
    k_deg<<<(N_NODES * 4 + 255) / 256, 256, 0, stream>>>(bst, erec, inv2);
    k_gather<<<(N_NODES + 3) / 4, 256, 0, stream>>>(bst, erec, inv2,
                                                    (const unsigned int*)Yb, out);
}